// Round 5
// baseline (1568.553 us; speedup 1.0000x reference)
//
#include <hip/hip_runtime.h>
#include <hip/hip_bf16.h>

#define N_NODES 100000
#define N_TYPES 10
#define N_EDGES 3200000
#define HIDDEN 256
#define EMBED 128
#define N_PAIRS 100000

#define N_BKT 8
#define BKT_DIV 12500          // nodes per bucket; slice = 12500*256B = 3.2 MB < 4 MB L2
#define ROWS_PB 144            // rows per spmm block; LDS acc = 144*128*2B = 36 KB

typedef _Float16 half2v __attribute__((ext_vector_type(2)));
typedef _Float16 half4v __attribute__((ext_vector_type(4)));
typedef _Float16 half8v __attribute__((ext_vector_type(8)));
typedef float floatx4 __attribute__((ext_vector_type(4)));

#define GLOBAL_AS __attribute__((address_space(1)))
#define LDS_AS __attribute__((address_space(3)))

static __device__ __forceinline__ void async_copy16(const void* g, void* lds) {
    __builtin_amdgcn_global_load_lds((const GLOBAL_AS unsigned int*)g,
                                     (LDS_AS unsigned int*)(void*)lds, 16, 0, 0);
}

// ---------------------------------------------------------------------------
// row_ptr from sorted rows (binary search, no atomics)
// ---------------------------------------------------------------------------
__global__ void build_rowptr_k(const int* __restrict__ rows, int* __restrict__ rp,
                               int n_nodes, int n_edges) {
    int n = blockIdx.x * blockDim.x + threadIdx.x;
    if (n > n_nodes) return;
    int lo = 0, hi = n_edges;
    while (lo < hi) {
        int mid = (lo + hi) >> 1;
        if (rows[mid] < n) lo = mid + 1; else hi = mid;
    }
    rp[n] = lo;
}

// ---------------------------------------------------------------------------
// Per-row counting sort of edges into N_BKT column buckets.
// One thread per row; packed 8x8-bit counters (max degree << 256);
// per-thread offset cursors live in LDS (conflict-free layout).
// Writes reordered (col, val) pairs as int2 + rp8[row][b] start offsets.
// ---------------------------------------------------------------------------
__global__ void bucket_sort_k(const int* __restrict__ rp, const int* __restrict__ cols,
                              const float* __restrict__ vals,
                              int* __restrict__ rp8, int2* __restrict__ ecv) {
    __shared__ int off_s[N_BKT][256];
    int t = threadIdx.x;
    int n = blockIdx.x * blockDim.x + t;
    if (n >= N_NODES) return;
    int e0 = rp[n], e1 = rp[n + 1];

    unsigned long long cnt = 0;
    for (int e = e0; e < e1; ++e) {
        int b = cols[e] / BKT_DIV;
        cnt += 1ull << (b * 8);
    }
    int s = e0;
#pragma unroll
    for (int b = 0; b < N_BKT; ++b) {
        off_s[b][t] = s;
        rp8[n * N_BKT + b] = s;
        s += (int)((cnt >> (b * 8)) & 0xff);
    }
    for (int e = e0; e < e1; ++e) {
        int c = cols[e];
        int b = c / BKT_DIV;
        int o = off_s[b][t]++;
        ecv[o] = make_int2(c, __float_as_int(vals[e]));
    }
}

// ---------------------------------------------------------------------------
// x halves: xa[n][0:128], xb[n][0:128] = fp16(node_emb[n][f] + type_emb[t][f])
// ---------------------------------------------------------------------------
__global__ void build_x16_k(const float* __restrict__ node_emb,
                            const float* __restrict__ type_emb,
                            const int* __restrict__ ntype,
                            _Float16* __restrict__ xa, _Float16* __restrict__ xb) {
    int idx = blockIdx.x * blockDim.x + threadIdx.x;
    int n  = idx >> 6;
    if (n >= N_NODES) return;
    int f4 = (idx & 63) * 4;
    int t = ntype[n];
    float4 a = *(const float4*)&node_emb[(size_t)n * HIDDEN + f4];
    float4 b = *(const float4*)&type_emb[(size_t)t * HIDDEN + f4];
    half4v o;
    o.x = (_Float16)(a.x + b.x);
    o.y = (_Float16)(a.y + b.y);
    o.z = (_Float16)(a.z + b.z);
    o.w = (_Float16)(a.w + b.w);
    if (f4 < 128)
        *(half4v*)&xa[(size_t)n * 128 + f4] = o;
    else
        *(half4v*)&xb[(size_t)n * 128 + (f4 - 128)] = o;
}

// ---------------------------------------------------------------------------
// Wt[n][k] = fp16(W[k][n])  for K=256 weights (W1, W2)
// ---------------------------------------------------------------------------
__global__ void transpose_w_k(const float* __restrict__ W, _Float16* __restrict__ Wt,
                              int K, int N) {
    int idx = blockIdx.x * blockDim.x + threadIdx.x;
    if (idx >= K * N) return;
    int k = idx & 255;
    int n = idx >> 8;
    Wt[idx] = (_Float16)W[(size_t)k * N + n];
}

// Wp1 [384,128] -> Wp1t [128][384] fp16
__global__ void transpose_wp1_k(const float* __restrict__ W, _Float16* __restrict__ Wt) {
    int k = threadIdx.x;
    int n = blockIdx.x;
    Wt[n * 384 + k] = (_Float16)W[(size_t)k * EMBED + n];
}

// ---------------------------------------------------------------------------
// Column-bucketed 128-wide spmm.
// Block = ROWS_PB rows, fp16 accumulators in LDS (36 KB -> 3 blocks/CU,
// grid of 695 fully co-resident). Buckets swept in order so all blocks
// gather from the same 3.2 MB table slice concurrently -> L2-resident.
// Coherence is a locality heuristic only; correctness is order-independent.
// ---------------------------------------------------------------------------
template <bool BIAS>
__global__ __launch_bounds__(256) void spmm_bkt_k(
        const int* __restrict__ rp, const int* __restrict__ rp8,
        const int2* __restrict__ ecv,
        const _Float16* __restrict__ table, const float* __restrict__ bias,
        _Float16* __restrict__ out, int out_stride, int out_off) {
    __shared__ half2v accs[ROWS_PB * 64];   // [row][lane] half2

    int t = threadIdx.x;
    int wave = t >> 6, lane = t & 63;
    int n0 = blockIdx.x * ROWS_PB;
    int fo = lane * 2;

    for (int i = t; i < ROWS_PB * 64; i += 256) accs[i] = (half2v)(_Float16)0.f;
    __syncthreads();

    for (int b = 0; b < N_BKT; ++b) {
        for (int r = wave; r < ROWS_PB; r += 4) {
            int row = n0 + r;
            if (row >= N_NODES) break;
            int e0 = __builtin_amdgcn_readfirstlane(rp8[row * N_BKT + b]);
            int e1 = __builtin_amdgcn_readfirstlane(
                         (b < N_BKT - 1) ? rp8[row * N_BKT + b + 1] : rp[row + 1]);
            if (e0 == e1) continue;
            float ax = 0.f, ay = 0.f;
            int e = e0;
            for (; e + 4 <= e1; e += 4) {
                int2 ev[4];
#pragma unroll
                for (int i = 0; i < 4; ++i) ev[i] = ecv[e + i];
                half2v h[4];
#pragma unroll
                for (int i = 0; i < 4; ++i)
                    h[i] = *(const half2v*)&table[(size_t)ev[i].x * 128 + fo];
#pragma unroll
                for (int i = 0; i < 4; ++i) {
                    float v = __int_as_float(ev[i].y);
                    ax += v * (float)h[i].x;
                    ay += v * (float)h[i].y;
                }
            }
            for (; e < e1; ++e) {
                int2 ev = ecv[e];
                half2v h = *(const half2v*)&table[(size_t)ev.x * 128 + fo];
                float v = __int_as_float(ev.y);
                ax += v * (float)h.x;
                ay += v * (float)h.y;
            }
            half2v a = accs[r * 64 + lane];
            a.x = (_Float16)((float)a.x + ax);
            a.y = (_Float16)((float)a.y + ay);
            accs[r * 64 + lane] = a;
        }
        __syncthreads();   // keep waves/blocks phase-aligned per bucket (locality only)
    }

    float bx = 0.f, by = 0.f;
    if (BIAS) { bx = bias[fo]; by = bias[fo + 1]; }
    for (int r = wave; r < ROWS_PB; r += 4) {
        int row = n0 + r;
        if (row >= N_NODES) break;
        half2v a = accs[r * 64 + lane];
        if (BIAS) {
            a.x = (_Float16)((float)a.x + bx);
            a.y = (_Float16)((float)a.y + by);
        }
        *(half2v*)&out[(size_t)row * out_stride + out_off + fo] = a;
    }
}

// ---------------------------------------------------------------------------
// fp16 MFMA GEMM: C16 = [relu](A @ Bt^T + bias), A [M,256], Bt [N,256]
// 128x128 tile, BK=32, 256 thr, global_load_lds width-16 staging
// ---------------------------------------------------------------------------
template <bool RELU, bool BIAS>
__global__ void gemm16_k(const _Float16* __restrict__ A,
                         const _Float16* __restrict__ Bt,
                         const float* __restrict__ bias,
                         _Float16* __restrict__ C,
                         int M, int N) {
    const int K = 256;
    __shared__ _Float16 As[128 * 32];
    __shared__ _Float16 Bs[128 * 32];

    int t = threadIdx.x;
    int lane = t & 63;
    int wave = t >> 6;
    int quad = lane >> 4;
    int m16 = lane & 15;
    int wr = wave >> 1, wc = wave & 1;
    int m0 = blockIdx.x * 128;
    int n0 = blockIdx.y * 128;

    int srow = t >> 2;
    int skoff = (t & 3) * 8;

    floatx4 acc[4][4];
#pragma unroll
    for (int i = 0; i < 4; ++i)
#pragma unroll
        for (int j = 0; j < 4; ++j)
            acc[i][j] = (floatx4)0.f;

    for (int k0 = 0; k0 < K; k0 += 32) {
        int ra0 = m0 + srow;       if (ra0 >= M) ra0 = M - 1;
        int ra1 = m0 + srow + 64;  if (ra1 >= M) ra1 = M - 1;
        async_copy16(&A[(size_t)ra0 * K + k0 + skoff], &As[srow * 32 + skoff]);
        async_copy16(&A[(size_t)ra1 * K + k0 + skoff], &As[(srow + 64) * 32 + skoff]);
        async_copy16(&Bt[(size_t)(n0 + srow) * K + k0 + skoff], &Bs[srow * 32 + skoff]);
        async_copy16(&Bt[(size_t)(n0 + srow + 64) * K + k0 + skoff], &Bs[(srow + 64) * 32 + skoff]);
        __syncthreads();

        half8v aF[4], bF[4];
#pragma unroll
        for (int i = 0; i < 4; ++i)
            aF[i] = *(const half8v*)&As[(wr * 64 + i * 16 + m16) * 32 + quad * 8];
#pragma unroll
        for (int j = 0; j < 4; ++j)
            bF[j] = *(const half8v*)&Bs[(wc * 64 + j * 16 + m16) * 32 + quad * 8];
#pragma unroll
        for (int i = 0; i < 4; ++i)
#pragma unroll
            for (int j = 0; j < 4; ++j)
                acc[i][j] = __builtin_amdgcn_mfma_f32_16x16x32_f16(aF[i], bF[j], acc[i][j], 0, 0, 0);
        __syncthreads();
    }

#pragma unroll
    for (int i = 0; i < 4; ++i) {
#pragma unroll
        for (int j = 0; j < 4; ++j) {
            int gr = m0 + wr * 64 + i * 16 + quad * 4;
            int gc = n0 + wc * 64 + j * 16 + m16;
            float bv = BIAS ? bias[gc] : 0.f;
#pragma unroll
            for (int r = 0; r < 4; ++r) {
                int row = gr + r;
                if (row < M) {
                    float v = acc[i][j][r] + bv;
                    if (RELU) v = v > 0.f ? v : 0.f;
                    C[(size_t)row * N + gc] = (_Float16)v;
                }
            }
        }
    }
}

// ---------------------------------------------------------------------------
// MFMA fp16 pair scorer: 128 pairs/block, K=384 in 3 regions of 128.
// Fs staged in LDS; Wp1t fragments read from global (L2-hot).
// ---------------------------------------------------------------------------
__global__ __launch_bounds__(256) void scorer_mfma_k(
        const _Float16* __restrict__ z16, const int* __restrict__ pairs,
        const _Float16* __restrict__ Wp1t, const float* __restrict__ bp1,
        const float* __restrict__ Wp2, const float* __restrict__ bp2,
        float* __restrict__ out, int P) {
    __shared__ _Float16 Fs[128][136];
    __shared__ int sidx[128], didx[128];
    __shared__ float red[128][2];

    int t  = threadIdx.x;
    int p0 = blockIdx.x * 128;

    if (t < 128) {
        int p = p0 + t;
        if (p >= P) p = P - 1;
        sidx[t] = pairs[p];
        didx[t] = pairs[P + p];
    }
    __syncthreads();

    int lane = t & 63, wave = t >> 6;
    int quad = lane >> 4, m16 = lane & 15;
    int wr = wave >> 1, wc = wave & 1;

    floatx4 acc[4][4];
#pragma unroll
    for (int i = 0; i < 4; ++i)
#pragma unroll
        for (int j = 0; j < 4; ++j)
            acc[i][j] = (floatx4)0.f;

    int pr = t & 127;
    int kh = (t >> 7) * 64;

    for (int r = 0; r < 3; ++r) {
        {
            const _Float16* zs = &z16[(size_t)sidx[pr] * EMBED + kh];
            const _Float16* zd = &z16[(size_t)didx[pr] * EMBED + kh];
            half8v f[8];
            if (r == 0) {
#pragma unroll
                for (int i = 0; i < 8; ++i) f[i] = *(const half8v*)&zs[i * 8];
            } else if (r == 1) {
#pragma unroll
                for (int i = 0; i < 8; ++i) f[i] = *(const half8v*)&zd[i * 8];
            } else {
#pragma unroll
                for (int i = 0; i < 8; ++i) {
                    half8v a = *(const half8v*)&zs[i * 8];
                    half8v b = *(const half8v*)&zd[i * 8];
                    f[i] = a * b;
                }
            }
#pragma unroll
            for (int i = 0; i < 8; ++i)
                *(half8v*)&Fs[pr][kh + i * 8] = f[i];
        }
        __syncthreads();

#pragma unroll
        for (int k0 = 0; k0 < 128; k0 += 32) {
            half8v aF[4], bF[4];
#pragma unroll
            for (int i = 0; i < 4; ++i)
                aF[i] = *(const half8v*)&Fs[wr * 64 + i * 16 + m16][k0 + quad * 8];
#pragma unroll
            for (int j = 0; j < 4; ++j)
                bF[j] = *(const half8v*)&Wp1t[(size_t)(wc * 64 + j * 16 + m16) * 384
                                              + r * 128 + k0 + quad * 8];
#pragma unroll
            for (int i = 0; i < 4; ++i)
#pragma unroll
                for (int j = 0; j < 4; ++j)
                    acc[i][j] = __builtin_amdgcn_mfma_f32_16x16x32_f16(aF[i], bF[j], acc[i][j], 0, 0, 0);
        }
        __syncthreads();
    }

    float w2v[4], b1v[4];
#pragma unroll
    for (int j = 0; j < 4; ++j) {
        int col = wc * 64 + j * 16 + m16;
        w2v[j] = Wp2[col];
        b1v[j] = bp1[col];
    }
#pragma unroll
    for (int i = 0; i < 4; ++i) {
#pragma unroll
        for (int rr = 0; rr < 4; ++rr) {
            float partial = 0.f;
#pragma unroll
            for (int j = 0; j < 4; ++j) {
                float v = acc[i][j][rr] + b1v[j];
                v = v > 0.f ? v : 0.f;
                partial += v * w2v[j];
            }
#pragma unroll
            for (int off = 1; off < 16; off <<= 1)
                partial += __shfl_xor(partial, off, 64);
            if (m16 == 0)
                red[wr * 64 + i * 16 + quad * 4 + rr][wc] = partial;
        }
    }
    __syncthreads();
    if (t < 128) {
        int p = p0 + t;
        if (p < P) out[p] = red[t][0] + red[t][1] + bp2[0];
    }
}

// ---------------------------------------------------------------------------
// Launch
// ---------------------------------------------------------------------------
extern "C" void kernel_launch(void* const* d_in, const int* in_sizes, int n_in,
                              void* d_out, int out_size, void* d_ws, size_t ws_size,
                              hipStream_t stream) {
    const int*   node_type_ids = (const int*)d_in[0];
    const int*   rows          = (const int*)d_in[1];
    const int*   cols          = (const int*)d_in[2];
    const float* edge_vals     = (const float*)d_in[3];
    const int*   pairs         = (const int*)d_in[4];
    const float* node_emb      = (const float*)d_in[5];
    const float* type_emb      = (const float*)d_in[6];
    const float* W1            = (const float*)d_in[7];
    const float* b1            = (const float*)d_in[8];
    const float* W2            = (const float*)d_in[9];
    const float* b2            = (const float*)d_in[10];
    const float* Wp1           = (const float*)d_in[11];
    const float* bp1           = (const float*)d_in[12];
    const float* Wp2           = (const float*)d_in[13];
    const float* bp2           = (const float*)d_in[14];
    float* out = (float*)d_out;

    const size_t MB = 1ull << 20;
    char* ws = (char*)d_ws;
    int*      rp   = (int*)(ws);                   // 0.4 MB
    int*      rp8  = (int*)(ws + 1 * MB);          // 3.2 MB
    int2*     ecv  = (int2*)(ws + 5 * MB);         // 25.6 MB
    _Float16* xa   = (_Float16*)(ws + 31 * MB);    // 25.6 MB
    _Float16* xb   = (_Float16*)(ws + 57 * MB);    // 25.6 MB
    _Float16* s1   = (_Float16*)(ws + 83 * MB);    // 51.2 MB
    _Float16* h16  = (_Float16*)(ws + 135 * MB);   // 51.2 MB
    _Float16* g16  = (_Float16*)(ws + 187 * MB);   // 25.6 MB
    _Float16* z16  = (_Float16*)(ws + 213 * MB);   // 25.6 MB
    _Float16* W1t  = (_Float16*)(ws + 239 * MB);
    _Float16* W2t  = (_Float16*)(ws + 240 * MB);
    _Float16* Wp1t = (_Float16*)(ws + 241 * MB);

    // prep
    build_rowptr_k<<<(N_NODES + 256) / 256, 256, 0, stream>>>(rows, rp, N_NODES, N_EDGES);
    bucket_sort_k<<<(N_NODES + 255) / 256, 256, 0, stream>>>(rp, cols, edge_vals, rp8, ecv);
    build_x16_k<<<(N_NODES * 64 + 255) / 256, 256, 0, stream>>>(node_emb, type_emb,
                                                                node_type_ids, xa, xb);
    transpose_w_k<<<(HIDDEN * HIDDEN + 255) / 256, 256, 0, stream>>>(W1, W1t, HIDDEN, HIDDEN);
    transpose_w_k<<<(HIDDEN * EMBED + 255) / 256, 256, 0, stream>>>(W2, W2t, HIDDEN, EMBED);
    transpose_wp1_k<<<EMBED, 3 * EMBED, 0, stream>>>(Wp1, Wp1t);

    const int SPMM_GRID = (N_NODES + ROWS_PB - 1) / ROWS_PB;   // 695

    // s1 = spmm(x) in two bucketed half passes
    spmm_bkt_k<false><<<SPMM_GRID, 256, 0, stream>>>(rp, rp8, ecv, xa, nullptr,
                                                     s1, HIDDEN, 0);
    spmm_bkt_k<false><<<SPMM_GRID, 256, 0, stream>>>(rp, rp8, ecv, xb, nullptr,
                                                     s1, HIDDEN, 128);

    // h = relu(s1 @ W1 + b1)
    {
        dim3 grid((N_NODES + 127) / 128, HIDDEN / 128);
        gemm16_k<true, true><<<grid, 256, 0, stream>>>(s1, W1t, b1, h16, N_NODES, HIDDEN);
    }

    // g = h @ W2   (z = spmm(g) + b2 by linearity)
    {
        dim3 grid((N_NODES + 127) / 128, EMBED / 128);
        gemm16_k<false, false><<<grid, 256, 0, stream>>>(h16, W2t, nullptr, g16, N_NODES, EMBED);
    }

    // z16 = spmm(g) + b2  (bucketed)
    spmm_bkt_k<true><<<SPMM_GRID, 256, 0, stream>>>(rp, rp8, ecv, g16, b2,
                                                    z16, EMBED, 0);

    // scorer
    scorer_mfma_k<<<(N_PAIRS + 127) / 128, 256, 0, stream>>>(z16, pairs, Wp1t, bp1,
                                                             Wp2, bp2, out, N_PAIRS);
}

// Round 6
// 789.542 us; speedup vs baseline: 1.9867x; 1.9867x over previous
//
#include <hip/hip_runtime.h>
#include <hip/hip_bf16.h>

#define N_NODES 100000
#define N_TYPES 10
#define N_EDGES 3200000
#define HIDDEN 256
#define EMBED 128
#define N_PAIRS 100000

#define N_BKT 8
#define BKT_DIV 12500          // table slice = 12500*256B = 3.2 MB < 4 MB per-XCD L2
#define ROWS_PB 144            // rows per spmm block; LDS acc = 144*128*2B = 36 KB
#define NCHUNK 695             // ceil(100000/144)

typedef _Float16 half2v __attribute__((ext_vector_type(2)));
typedef _Float16 half4v __attribute__((ext_vector_type(4)));
typedef _Float16 half8v __attribute__((ext_vector_type(8)));
typedef float floatx4 __attribute__((ext_vector_type(4)));

#define GLOBAL_AS __attribute__((address_space(1)))
#define LDS_AS __attribute__((address_space(3)))

static __device__ __forceinline__ void async_copy16(const void* g, void* lds) {
    __builtin_amdgcn_global_load_lds((const GLOBAL_AS unsigned int*)g,
                                     (LDS_AS unsigned int*)(void*)lds, 16, 0, 0);
}

// ---------------------------------------------------------------------------
// row_ptr from sorted rows (binary search, no atomics)
// ---------------------------------------------------------------------------
__global__ void build_rowptr_k(const int* __restrict__ rows, int* __restrict__ rp,
                               int n_nodes, int n_edges) {
    int n = blockIdx.x * blockDim.x + threadIdx.x;
    if (n > n_nodes) return;
    int lo = 0, hi = n_edges;
    while (lo < hi) {
        int mid = (lo + hi) >> 1;
        if (rows[mid] < n) lo = mid + 1; else hi = mid;
    }
    rp[n] = lo;
}

// ---------------------------------------------------------------------------
// Per-chunk counting sort of edges into (bucket, row)-major order.
// One block per chunk of ROWS_PB rows. Produces:
//   ecv[dst]  = (col | rowlocal<<17, val_bits)   contiguous per (chunk,bucket)
//   rp_wave[(chunk*8 + b)*4 + q] = start of wave q's rows [q*36,(q+1)*36) in bucket b
// Segment ends = next entry (layout is fully contiguous); sentinel at the end.
// ---------------------------------------------------------------------------
__global__ __launch_bounds__(256) void bucket2_k(
        const int* __restrict__ rp, const int* __restrict__ cols,
        const float* __restrict__ vals,
        int* __restrict__ rp_wave, int2* __restrict__ ecv) {
    __shared__ int cnt_s[ROWS_PB][N_BKT];
    __shared__ int btot[N_BKT];
    __shared__ int bbase[N_BKT];

    int t = threadIdx.x;
    int c = blockIdx.x;
    int n0 = c * ROWS_PB;
    int n = n0 + t;
    int e0 = 0, e1 = 0;
    if (t < ROWS_PB && n < N_NODES) { e0 = rp[n]; e1 = rp[n + 1]; }
    int chunk_e0 = rp[min(n0, N_NODES)];

    if (blockIdx.x == 0 && t == 255) rp_wave[NCHUNK * N_BKT * 4] = N_EDGES;

    // 1. count per row per bucket (packed 8x8-bit; per-bucket degree << 256)
    unsigned long long cnt = 0;
    for (int e = e0; e < e1; ++e) {
        int b = cols[e] / BKT_DIV;
        cnt += 1ull << (b * 8);
    }
    if (t < ROWS_PB) {
#pragma unroll
        for (int b = 0; b < N_BKT; ++b)
            cnt_s[t][b] = (int)((cnt >> (b * 8)) & 0xff);
    }
    __syncthreads();

    // 2. exclusive prefix over rows within each bucket (serial per bucket)
    if (t < N_BKT) {
        int s = 0;
        for (int r = 0; r < ROWS_PB; ++r) {
            int v = cnt_s[r][t];
            cnt_s[r][t] = s;
            s += v;
        }
        btot[t] = s;
    }
    __syncthreads();
    // 3. exclusive prefix over buckets
    if (t == 0) {
        int s = 0;
#pragma unroll
        for (int b = 0; b < N_BKT; ++b) { bbase[b] = s; s += btot[b]; }
    }
    __syncthreads();
    // 4. absolute starts; write wave boundaries
    if (t < ROWS_PB) {
#pragma unroll
        for (int b = 0; b < N_BKT; ++b)
            cnt_s[t][b] += chunk_e0 + bbase[b];
        if ((t % (ROWS_PB / 4)) == 0) {
            int q = t / (ROWS_PB / 4);
#pragma unroll
            for (int b = 0; b < N_BKT; ++b)
                rp_wave[(c * N_BKT + b) * 4 + q] = cnt_s[t][b];
        }
    }
    __syncthreads();
    // 5. scatter (thread-exclusive LDS cursors)
    if (t < ROWS_PB) {
        for (int e = e0; e < e1; ++e) {
            int col = cols[e];
            int b = col / BKT_DIV;
            int dst = cnt_s[t][b]++;
            ecv[dst] = make_int2(col | (t << 17), __float_as_int(vals[e]));
        }
    }
}

// ---------------------------------------------------------------------------
// x halves: xa[n][0:128], xb[n][0:128] = fp16(node_emb[n][f] + type_emb[t][f])
// ---------------------------------------------------------------------------
__global__ void build_x16_k(const float* __restrict__ node_emb,
                            const float* __restrict__ type_emb,
                            const int* __restrict__ ntype,
                            _Float16* __restrict__ xa, _Float16* __restrict__ xb) {
    int idx = blockIdx.x * blockDim.x + threadIdx.x;
    int n  = idx >> 6;
    if (n >= N_NODES) return;
    int f4 = (idx & 63) * 4;
    int t = ntype[n];
    float4 a = *(const float4*)&node_emb[(size_t)n * HIDDEN + f4];
    float4 b = *(const float4*)&type_emb[(size_t)t * HIDDEN + f4];
    half4v o;
    o.x = (_Float16)(a.x + b.x);
    o.y = (_Float16)(a.y + b.y);
    o.z = (_Float16)(a.z + b.z);
    o.w = (_Float16)(a.w + b.w);
    if (f4 < 128)
        *(half4v*)&xa[(size_t)n * 128 + f4] = o;
    else
        *(half4v*)&xb[(size_t)n * 128 + (f4 - 128)] = o;
}

// ---------------------------------------------------------------------------
// Wt[n][k] = fp16(W[k][n])  for K=256 weights (W1, W2)
// ---------------------------------------------------------------------------
__global__ void transpose_w_k(const float* __restrict__ W, _Float16* __restrict__ Wt,
                              int K, int N) {
    int idx = blockIdx.x * blockDim.x + threadIdx.x;
    if (idx >= K * N) return;
    int k = idx & 255;
    int n = idx >> 8;
    Wt[idx] = (_Float16)W[(size_t)k * N + n];
}

// Wp1 [384,128] -> Wp1t [128][384] fp16
__global__ void transpose_wp1_k(const float* __restrict__ W, _Float16* __restrict__ Wt) {
    int k = threadIdx.x;
    int n = blockIdx.x;
    Wt[n * 384 + k] = (_Float16)W[(size_t)k * EMBED + n];
}

// ---------------------------------------------------------------------------
// Bucketed edge-streamed 128-wide spmm.
// Block = ROWS_PB rows (fp16 LDS accs, 36 KB -> 4 blocks/CU, grid 695 fully
// co-resident). Buckets swept in order: all blocks gather from the same
// 3.2 MB table slice concurrently -> L2-resident (locality heuristic only).
// Each wave streams its contiguous (chunk,bucket,wave) edge segment with a
// 16-deep gather batch; fp32 register run-accumulation, flush on row change.
// Rows are wave-exclusive -> no LDS races.
// ---------------------------------------------------------------------------
template <bool BIAS>
__global__ __launch_bounds__(256) void spmm_bkt2_k(
        const int* __restrict__ rp_wave, const int2* __restrict__ ecv,
        const _Float16* __restrict__ table, const float* __restrict__ bias,
        _Float16* __restrict__ out, int out_stride, int out_off) {
    __shared__ half2v accs[ROWS_PB * 64];   // [row][lane] half2

    int t = threadIdx.x;
    int wave = t >> 6, lane = t & 63;
    int c = blockIdx.x;
    int n0 = c * ROWS_PB;
    int fo = lane * 2;

    for (int i = t; i < ROWS_PB * 64; i += 256) accs[i] = (half2v)(_Float16)0.f;
    __syncthreads();

    for (int b = 0; b < N_BKT; ++b) {
        int seg = (c * N_BKT + b) * 4 + wave;
        int e0 = __builtin_amdgcn_readfirstlane(rp_wave[seg]);
        int e1 = __builtin_amdgcn_readfirstlane(rp_wave[seg + 1]);

        int run = -1;
        float ax = 0.f, ay = 0.f;
        int e = e0;
        for (; e + 16 <= e1; e += 16) {
            int2 ev[16];
#pragma unroll
            for (int i = 0; i < 16; ++i) ev[i] = ecv[e + i];
            half2v h[16];
#pragma unroll
            for (int i = 0; i < 16; ++i) {
                int colx = __builtin_amdgcn_readfirstlane(ev[i].x) & 0x1FFFF;
                h[i] = *(const half2v*)&table[(size_t)colx * 128 + fo];
            }
#pragma unroll
            for (int i = 0; i < 16; ++i) {
                int rl = __builtin_amdgcn_readfirstlane(ev[i].x) >> 17;
                if (rl != run) {
                    if (run >= 0) {
                        half2v a = accs[run * 64 + lane];
                        a.x = (_Float16)((float)a.x + ax);
                        a.y = (_Float16)((float)a.y + ay);
                        accs[run * 64 + lane] = a;
                    }
                    run = rl; ax = 0.f; ay = 0.f;
                }
                float v = __int_as_float(ev[i].y);
                ax += v * (float)h[i].x;
                ay += v * (float)h[i].y;
            }
        }
        for (; e < e1; ++e) {
            int2 ev = ecv[e];
            int m = __builtin_amdgcn_readfirstlane(ev.x);
            half2v hh = *(const half2v*)&table[(size_t)(m & 0x1FFFF) * 128 + fo];
            int rl = m >> 17;
            if (rl != run) {
                if (run >= 0) {
                    half2v a = accs[run * 64 + lane];
                    a.x = (_Float16)((float)a.x + ax);
                    a.y = (_Float16)((float)a.y + ay);
                    accs[run * 64 + lane] = a;
                }
                run = rl; ax = 0.f; ay = 0.f;
            }
            float v = __int_as_float(ev.y);
            ax += v * (float)hh.x;
            ay += v * (float)hh.y;
        }
        if (run >= 0) {
            half2v a = accs[run * 64 + lane];
            a.x = (_Float16)((float)a.x + ax);
            a.y = (_Float16)((float)a.y + ay);
            accs[run * 64 + lane] = a;
        }
        __syncthreads();   // phase alignment across waves/blocks (locality only)
    }

    float bx = 0.f, by = 0.f;
    if (BIAS) { bx = bias[fo]; by = bias[fo + 1]; }
    for (int r = wave; r < ROWS_PB; r += 4) {
        int row = n0 + r;
        if (row >= N_NODES) break;
        half2v a = accs[r * 64 + lane];
        if (BIAS) {
            a.x = (_Float16)((float)a.x + bx);
            a.y = (_Float16)((float)a.y + by);
        }
        *(half2v*)&out[(size_t)row * out_stride + out_off + fo] = a;
    }
}

// ---------------------------------------------------------------------------
// fp16 MFMA GEMM: C16 = [relu](A @ Bt^T + bias), A [M,256], Bt [N,256]
// 128x128 tile, BK=32, 256 thr, global_load_lds width-16 staging
// ---------------------------------------------------------------------------
template <bool RELU, bool BIAS>
__global__ void gemm16_k(const _Float16* __restrict__ A,
                         const _Float16* __restrict__ Bt,
                         const float* __restrict__ bias,
                         _Float16* __restrict__ C,
                         int M, int N) {
    const int K = 256;
    __shared__ _Float16 As[128 * 32];
    __shared__ _Float16 Bs[128 * 32];

    int t = threadIdx.x;
    int lane = t & 63;
    int wave = t >> 6;
    int quad = lane >> 4;
    int m16 = lane & 15;
    int wr = wave >> 1, wc = wave & 1;
    int m0 = blockIdx.x * 128;
    int n0 = blockIdx.y * 128;

    int srow = t >> 2;
    int skoff = (t & 3) * 8;

    floatx4 acc[4][4];
#pragma unroll
    for (int i = 0; i < 4; ++i)
#pragma unroll
        for (int j = 0; j < 4; ++j)
            acc[i][j] = (floatx4)0.f;

    for (int k0 = 0; k0 < K; k0 += 32) {
        int ra0 = m0 + srow;       if (ra0 >= M) ra0 = M - 1;
        int ra1 = m0 + srow + 64;  if (ra1 >= M) ra1 = M - 1;
        async_copy16(&A[(size_t)ra0 * K + k0 + skoff], &As[srow * 32 + skoff]);
        async_copy16(&A[(size_t)ra1 * K + k0 + skoff], &As[(srow + 64) * 32 + skoff]);
        async_copy16(&Bt[(size_t)(n0 + srow) * K + k0 + skoff], &Bs[srow * 32 + skoff]);
        async_copy16(&Bt[(size_t)(n0 + srow + 64) * K + k0 + skoff], &Bs[(srow + 64) * 32 + skoff]);
        __syncthreads();

        half8v aF[4], bF[4];
#pragma unroll
        for (int i = 0; i < 4; ++i)
            aF[i] = *(const half8v*)&As[(wr * 64 + i * 16 + m16) * 32 + quad * 8];
#pragma unroll
        for (int j = 0; j < 4; ++j)
            bF[j] = *(const half8v*)&Bs[(wc * 64 + j * 16 + m16) * 32 + quad * 8];
#pragma unroll
        for (int i = 0; i < 4; ++i)
#pragma unroll
            for (int j = 0; j < 4; ++j)
                acc[i][j] = __builtin_amdgcn_mfma_f32_16x16x32_f16(aF[i], bF[j], acc[i][j], 0, 0, 0);
        __syncthreads();
    }

#pragma unroll
    for (int i = 0; i < 4; ++i) {
#pragma unroll
        for (int j = 0; j < 4; ++j) {
            int gr = m0 + wr * 64 + i * 16 + quad * 4;
            int gc = n0 + wc * 64 + j * 16 + m16;
            float bv = BIAS ? bias[gc] : 0.f;
#pragma unroll
            for (int r = 0; r < 4; ++r) {
                int row = gr + r;
                if (row < M) {
                    float v = acc[i][j][r] + bv;
                    if (RELU) v = v > 0.f ? v : 0.f;
                    C[(size_t)row * N + gc] = (_Float16)v;
                }
            }
        }
    }
}

// ---------------------------------------------------------------------------
// MFMA fp16 pair scorer: 128 pairs/block, K=384 in 3 regions of 128.
// Fs staged in LDS; Wp1t fragments read from global (L2-hot).
// ---------------------------------------------------------------------------
__global__ __launch_bounds__(256) void scorer_mfma_k(
        const _Float16* __restrict__ z16, const int* __restrict__ pairs,
        const _Float16* __restrict__ Wp1t, const float* __restrict__ bp1,
        const float* __restrict__ Wp2, const float* __restrict__ bp2,
        float* __restrict__ out, int P) {
    __shared__ _Float16 Fs[128][136];
    __shared__ int sidx[128], didx[128];
    __shared__ float red[128][2];

    int t  = threadIdx.x;
    int p0 = blockIdx.x * 128;

    if (t < 128) {
        int p = p0 + t;
        if (p >= P) p = P - 1;
        sidx[t] = pairs[p];
        didx[t] = pairs[P + p];
    }
    __syncthreads();

    int lane = t & 63, wave = t >> 6;
    int quad = lane >> 4, m16 = lane & 15;
    int wr = wave >> 1, wc = wave & 1;

    floatx4 acc[4][4];
#pragma unroll
    for (int i = 0; i < 4; ++i)
#pragma unroll
        for (int j = 0; j < 4; ++j)
            acc[i][j] = (floatx4)0.f;

    int pr = t & 127;
    int kh = (t >> 7) * 64;

    for (int r = 0; r < 3; ++r) {
        {
            const _Float16* zs = &z16[(size_t)sidx[pr] * EMBED + kh];
            const _Float16* zd = &z16[(size_t)didx[pr] * EMBED + kh];
            half8v f[8];
            if (r == 0) {
#pragma unroll
                for (int i = 0; i < 8; ++i) f[i] = *(const half8v*)&zs[i * 8];
            } else if (r == 1) {
#pragma unroll
                for (int i = 0; i < 8; ++i) f[i] = *(const half8v*)&zd[i * 8];
            } else {
#pragma unroll
                for (int i = 0; i < 8; ++i) {
                    half8v a = *(const half8v*)&zs[i * 8];
                    half8v b = *(const half8v*)&zd[i * 8];
                    f[i] = a * b;
                }
            }
#pragma unroll
            for (int i = 0; i < 8; ++i)
                *(half8v*)&Fs[pr][kh + i * 8] = f[i];
        }
        __syncthreads();

#pragma unroll
        for (int k0 = 0; k0 < 128; k0 += 32) {
            half8v aF[4], bF[4];
#pragma unroll
            for (int i = 0; i < 4; ++i)
                aF[i] = *(const half8v*)&Fs[wr * 64 + i * 16 + m16][k0 + quad * 8];
#pragma unroll
            for (int j = 0; j < 4; ++j)
                bF[j] = *(const half8v*)&Wp1t[(size_t)(wc * 64 + j * 16 + m16) * 384
                                              + r * 128 + k0 + quad * 8];
#pragma unroll
            for (int i = 0; i < 4; ++i)
#pragma unroll
                for (int j = 0; j < 4; ++j)
                    acc[i][j] = __builtin_amdgcn_mfma_f32_16x16x32_f16(aF[i], bF[j], acc[i][j], 0, 0, 0);
        }
        __syncthreads();
    }

    float w2v[4], b1v[4];
#pragma unroll
    for (int j = 0; j < 4; ++j) {
        int col = wc * 64 + j * 16 + m16;
        w2v[j] = Wp2[col];
        b1v[j] = bp1[col];
    }
#pragma unroll
    for (int i = 0; i < 4; ++i) {
#pragma unroll
        for (int rr = 0; rr < 4; ++rr) {
            float partial = 0.f;
#pragma unroll
            for (int j = 0; j < 4; ++j) {
                float v = acc[i][j][rr] + b1v[j];
                v = v > 0.f ? v : 0.f;
                partial += v * w2v[j];
            }
#pragma unroll
            for (int off = 1; off < 16; off <<= 1)
                partial += __shfl_xor(partial, off, 64);
            if (m16 == 0)
                red[wr * 64 + i * 16 + quad * 4 + rr][wc] = partial;
        }
    }
    __syncthreads();
    if (t < 128) {
        int p = p0 + t;
        if (p < P) out[p] = red[t][0] + red[t][1] + bp2[0];
    }
}

// ---------------------------------------------------------------------------
// Launch
// ---------------------------------------------------------------------------
extern "C" void kernel_launch(void* const* d_in, const int* in_sizes, int n_in,
                              void* d_out, int out_size, void* d_ws, size_t ws_size,
                              hipStream_t stream) {
    const int*   node_type_ids = (const int*)d_in[0];
    const int*   rows          = (const int*)d_in[1];
    const int*   cols          = (const int*)d_in[2];
    const float* edge_vals     = (const float*)d_in[3];
    const int*   pairs         = (const int*)d_in[4];
    const float* node_emb      = (const float*)d_in[5];
    const float* type_emb      = (const float*)d_in[6];
    const float* W1            = (const float*)d_in[7];
    const float* b1            = (const float*)d_in[8];
    const float* W2            = (const float*)d_in[9];
    const float* b2            = (const float*)d_in[10];
    const float* Wp1           = (const float*)d_in[11];
    const float* bp1           = (const float*)d_in[12];
    const float* Wp2           = (const float*)d_in[13];
    const float* bp2           = (const float*)d_in[14];
    float* out = (float*)d_out;

    const size_t MB = 1ull << 20;
    char* ws = (char*)d_ws;
    int*      rp      = (int*)(ws);                   // 0.4 MB
    int*      rp_wave = (int*)(ws + 1 * MB);          // 89 KB
    int2*     ecv     = (int2*)(ws + 2 * MB);         // 25.6 MB
    _Float16* xa      = (_Float16*)(ws + 28 * MB);    // 25.6 MB
    _Float16* xb      = (_Float16*)(ws + 54 * MB);    // 25.6 MB
    _Float16* s1      = (_Float16*)(ws + 80 * MB);    // 51.2 MB
    _Float16* h16     = (_Float16*)(ws + 132 * MB);   // 51.2 MB
    _Float16* g16     = (_Float16*)(ws + 184 * MB);   // 25.6 MB
    _Float16* z16     = (_Float16*)(ws + 210 * MB);   // 25.6 MB
    _Float16* W1t     = (_Float16*)(ws + 236 * MB);
    _Float16* W2t     = (_Float16*)(ws + 237 * MB);
    _Float16* Wp1t    = (_Float16*)(ws + 238 * MB);

    // prep
    build_rowptr_k<<<(N_NODES + 256) / 256, 256, 0, stream>>>(rows, rp, N_NODES, N_EDGES);
    bucket2_k<<<NCHUNK, 256, 0, stream>>>(rp, cols, edge_vals, rp_wave, ecv);
    build_x16_k<<<(N_NODES * 64 + 255) / 256, 256, 0, stream>>>(node_emb, type_emb,
                                                                node_type_ids, xa, xb);
    transpose_w_k<<<(HIDDEN * HIDDEN + 255) / 256, 256, 0, stream>>>(W1, W1t, HIDDEN, HIDDEN);
    transpose_w_k<<<(HIDDEN * EMBED + 255) / 256, 256, 0, stream>>>(W2, W2t, HIDDEN, EMBED);
    transpose_wp1_k<<<EMBED, 3 * EMBED, 0, stream>>>(Wp1, Wp1t);

    // s1 = spmm(x) in two bucketed half passes
    spmm_bkt2_k<false><<<NCHUNK, 256, 0, stream>>>(rp_wave, ecv, xa, nullptr,
                                                   s1, HIDDEN, 0);
    spmm_bkt2_k<false><<<NCHUNK, 256, 0, stream>>>(rp_wave, ecv, xb, nullptr,
                                                   s1, HIDDEN, 128);

    // h = relu(s1 @ W1 + b1)
    {
        dim3 grid((N_NODES + 127) / 128, HIDDEN / 128);
        gemm16_k<true, true><<<grid, 256, 0, stream>>>(s1, W1t, b1, h16, N_NODES, HIDDEN);
    }

    // g = h @ W2   (z = spmm(g) + b2 by linearity)
    {
        dim3 grid((N_NODES + 127) / 128, EMBED / 128);
        gemm16_k<false, false><<<grid, 256, 0, stream>>>(h16, W2t, nullptr, g16, N_NODES, EMBED);
    }

    // z16 = spmm(g) + b2  (bucketed)
    spmm_bkt2_k<true><<<NCHUNK, 256, 0, stream>>>(rp_wave, ecv, g16, b2,
                                                  z16, EMBED, 0);

    // scorer
    scorer_mfma_k<<<(N_PAIRS + 127) / 128, 256, 0, stream>>>(z16, pairs, Wp1t, bp1,
                                                             Wp2, bp2, out, N_PAIRS);
}